// Round 1
// baseline (241.325 us; speedup 1.0000x reference)
//
#include <hip/hip_runtime.h>
#include <hip/hip_bf16.h>

// Problem constants (from reference setup_inputs)
#define D     128
#define K0    50
#define NCOL  51      // output columns: 50 (centers0) + 1 (centers1)
#define NT    12      // 192 GEMM output cols = 8 Y-tiles (quad form) + 4 cross-tiles
#define TB    64      // batch rows per block

typedef __attribute__((ext_vector_type(4))) float  f32x4;
typedef __attribute__((ext_vector_type(8))) short  short8x;  // 8 bf16 in 4 VGPRs

__device__ inline short f2bf(float x) {
    __hip_bfloat16 h = __float2bfloat16(x);
    return __builtin_bit_cast(short, h);
}
__device__ inline float bf2f(short s) {
    union { unsigned u; float f; } cv;
    cv.u = ((unsigned)(unsigned short)s) << 16;
    return cv.f;
}

// ---------------------------------------------------------------------------
// Setup: build G = [A0 | M0 | M1 | 0] (128 x 192) in bf16, stored directly in
// MFMA B-fragment order: Gws[kstep][ntile][lane][j] = G[kstep*32+(lane>>4)*8+j]
//                                                      [ntile*16+(lane&15)]
//   A0 = V diag(b0) V^T           (cols 0..127)
//   M0[:,k] = V (b0 . c0[k])      (cols 128..177)
//   M1      = V (b1 . c1[0])      (col 178), cols 179..191 zero
// Block 48 computes cc[k] = sum_e beta.(c^2).
// ---------------------------------------------------------------------------
__global__ __launch_bounds__(128) void setup_kernel(
    const float* __restrict__ bw,   // [2][128]
    const float* __restrict__ V,    // [128][128]
    const float* __restrict__ c0,   // [50][128]
    const float* __restrict__ c1,   // [1][128]
    short* __restrict__ Gws,        // bf16 [4][12][64][8]
    float* __restrict__ ccws)       // [51]
{
    const int blk = blockIdx.x;
    const int t   = threadIdx.x;
    __shared__ float beta0[D];
    __shared__ float Vd[32][D];     // V rows for this kstep (d side)
    __shared__ float Bn[16][D];     // V rows / center rows for this ntile (n side)

    if (t < D) {
        float b0 = bw[t], b1 = bw[D + t];
        beta0[t] = 1.0f / (1.0f + expf(b1 - b0));   // softmax over axis 0
    }

    if (blk == 48) {                 // cc terms
        __syncthreads();
        if (t < NCOL) {
            const float* cr = (t < K0) ? (c0 + (size_t)t * D) : c1;
            float s = 0.f;
            for (int e = 0; e < D; ++e) {
                float b = beta0[e];
                if (t == K0) b = 1.0f - b;
                float cv = cr[e];
                s += b * cv * cv;
            }
            ccws[t] = s;
        }
        return;
    }

    const int kstep = blk / NT;      // 0..3
    const int ntile = blk % NT;      // 0..11

    // stage V rows [kstep*32, kstep*32+32)
    for (int i = t; i < 32 * (D / 4); i += 128)
        ((f32x4*)Vd)[i] = ((const f32x4*)(V + (size_t)kstep * 32 * D))[i];
    // stage n-side rows
    for (int i = t; i < 16 * (D / 4); i += 128) {
        int r = i / (D / 4);
        int n = ntile * 16 + r;
        f32x4 v;
        if (n < D)            v = ((const f32x4*)(V + (size_t)n * D))[i % (D / 4)];
        else if (n - D < K0)  v = ((const f32x4*)(c0 + (size_t)(n - D) * D))[i % (D / 4)];
        else if (n - D == K0) v = ((const f32x4*)c1)[i % (D / 4)];
        else                  v = f32x4{0.f, 0.f, 0.f, 0.f};
        ((f32x4*)Bn)[i] = v;
    }
    __syncthreads();

    const int lane  = t >> 1;
    const int jbase = (t & 1) * 4;
    const int nl    = lane & 15;
    const int n     = ntile * 16 + nl;
    const bool useB1 = (n == D + K0);   // col 178 uses beta1
    short res[4];
    for (int jj = 0; jj < 4; ++jj) {
        int dl = (lane >> 4) * 8 + jbase + jj;
        float s = 0.f;
        #pragma unroll 8
        for (int e = 0; e < D; ++e) {
            float b = useB1 ? (1.0f - beta0[e]) : beta0[e];
            s += Vd[dl][e] * b * Bn[nl][e];
        }
        res[jj] = f2bf(s);
    }
    short* dst = Gws + ((size_t)(blk * 64 + lane)) * 8 + jbase;
    for (int jj = 0; jj < 4; ++jj) dst[jj] = res[jj];
}

// ---------------------------------------------------------------------------
// Main: per block, 64 rows. Y = z @ G via mfma_f32_16x16x32_bf16 (4 k-steps x
// 12 n-tiles per wave, 16 rows/wave). Epilogue: zz0 = sum z.Y[:,0:128],
// nrm = sum z^2, out[b,k] = zz0 + cc[k] - 2*Y[:,128+k] (k=50 uses nrm-zz0).
// ---------------------------------------------------------------------------
__global__ __launch_bounds__(256, 2) void main_kernel(
    const float* __restrict__ z,    // [B][128]
    const short* __restrict__ Gws,  // bf16 frag layout [4][12][64][8]
    const float* __restrict__ ccws, // [51]
    float* __restrict__ out)        // [B][51]
{
    __shared__ __align__(16) short Gs[4 * NT * 64 * 8];  // 49152 B
    __shared__ __align__(16) short zbf[TB][D];           // 16384 B (total 64 KB)

    const int t    = threadIdx.x;
    const int wave = t >> 6;
    const int lane = t & 63;
    const int c    = lane & 15;     // col within tile / A-row within wave tile
    const int q    = lane >> 4;     // quad
    const size_t rowbase = (size_t)blockIdx.x * TB;

    // ---- stage G (48 KB, L2-resident) ----
    for (int i = t; i < 4 * NT * 64 * 8 / 8; i += 256)
        ((int4*)Gs)[i] = ((const int4*)Gws)[i];

    // ---- load A fragments straight from global in fragment order ----
    const int arow = wave * 16 + c;                 // this lane's local row
    const float* zrow = z + (rowbase + arow) * D;
    short8x afrag[4];
    #pragma unroll
    for (int ks = 0; ks < 4; ++ks) {
        const float* p = zrow + ks * 32 + q * 8;
        f32x4 v0 = *(const f32x4*)p;
        f32x4 v1 = *(const f32x4*)(p + 4);
        short8x a;
        a[0] = f2bf(v0.x); a[1] = f2bf(v0.y); a[2] = f2bf(v0.z); a[3] = f2bf(v0.w);
        a[4] = f2bf(v1.x); a[5] = f2bf(v1.y); a[6] = f2bf(v1.z); a[7] = f2bf(v1.w);
        afrag[ks] = a;
        *(short8x*)(&zbf[arow][ks * 32 + q * 8]) = a;   // epilogue copy
    }
    __syncthreads();

    // ---- MFMA main loop: 48 x (ds_read_b128 + mfma) per wave ----
    f32x4 acc[NT];
    #pragma unroll
    for (int nt = 0; nt < NT; ++nt) acc[nt] = f32x4{0.f, 0.f, 0.f, 0.f};
    #pragma unroll
    for (int ks = 0; ks < 4; ++ks) {
        #pragma unroll
        for (int nt = 0; nt < NT; ++nt) {
            short8x bfrg = *(const short8x*)&Gs[((ks * NT + nt) * 64 + lane) * 8];
            acc[nt] = __builtin_amdgcn_mfma_f32_16x16x32_bf16(afrag[ks], bfrg, acc[nt], 0, 0, 0);
        }
    }

    // ---- epilogue: zz0 = z.Y, nrm = z.z (C layout: row=q*4+r, col=c) ----
    float qp[4] = {0.f, 0.f, 0.f, 0.f};
    float np[4] = {0.f, 0.f, 0.f, 0.f};
    #pragma unroll
    for (int nt = 0; nt < 8; ++nt) {
        #pragma unroll
        for (int r = 0; r < 4; ++r) {
            float zv = bf2f(zbf[wave * 16 + q * 4 + r][nt * 16 + c]);
            qp[r] += zv * acc[nt][r];
            np[r] += zv * zv;
        }
    }
    #pragma unroll
    for (int s = 1; s < 16; s <<= 1) {
        #pragma unroll
        for (int r = 0; r < 4; ++r) {
            qp[r] += __shfl_xor(qp[r], s, 64);
            np[r] += __shfl_xor(np[r], s, 64);
        }
    }

    #pragma unroll
    for (int nt = 8; nt < NT; ++nt) {
        int k = (nt - 8) * 16 + c;
        if (k <= K0) {
            float ccv = ccws[k];
            #pragma unroll
            for (int r = 0; r < 4; ++r) {
                size_t row = rowbase + wave * 16 + q * 4 + r;
                float zz = (k < K0) ? qp[r] : (np[r] - qp[r]);
                out[row * NCOL + k] = zz + ccv - 2.0f * acc[nt][r];
            }
        }
    }
}

extern "C" void kernel_launch(void* const* d_in, const int* in_sizes, int n_in,
                              void* d_out, int out_size, void* d_ws, size_t ws_size,
                              hipStream_t stream) {
    const float* z  = (const float*)d_in[0];
    const float* bw = (const float*)d_in[1];
    const float* V  = (const float*)d_in[2];
    const float* c0 = (const float*)d_in[3];
    const float* c1 = (const float*)d_in[4];
    float* out = (float*)d_out;

    short* Gws  = (short*)d_ws;                              // 49152 B bf16 frags
    float* ccws = (float*)((char*)d_ws + 4 * NT * 64 * 8 * 2);

    const int B = in_sizes[0] / D;   // 262144

    setup_kernel<<<49, 128, 0, stream>>>(bw, V, c0, c1, Gws, ccws);
    main_kernel<<<B / TB, 256, 0, stream>>>(z, Gws, ccws, out);
}